// Round 9
// baseline (229.481 us; speedup 1.0000x reference)
//
#include <hip/hip_runtime.h>

// HungarianCELoss — analytic collapse of the 120-perm matching.
// targets has only 2 distinct rows (fg, bg=1-fg) => argmin over perms ==
// argmin_k (cost_fg[k]-cost_bg[k]), ties -> smallest k (lex order of perms).
// Per-element identities (x = slot logit, fg = target):
//   d  = softplus(x) - x = log1p(exp(-|x|)) + max(-x,0);  sigmoid(x) = exp(-d)
//   sum_k A_k = sum d (all k,n) + sum_k XF_k,  C_k = 2*XF_k - X_k
//   answer = [sum_k A_k - C_{k*}] summed over b, / (B*K*N)
//
// R13: VGPR-dest loads cap in-flight bytes at ~2-3 KB/CU (R8-R12: ~2.1-2.6
// TB/s at any occupancy; Little's law needs ~9.2 KB/CU for 6.3 TB/s).
// Switch the stream to global_load_lds DMA: no VGPR destination, so
// outstanding loads are bounded by vmcnt(63), not registers.
//   - 256 blocks, one per CU, zero tail. Block = (b, quarter), 6 streams.
//   - LDS 3 x 6 x 4 KB = 72 KB, triple-buffered, depth-2 tile prefetch:
//     12 x 16 B x 256 thr = 48 KB in flight per CU (5x saturation need).
//   - wave-private LDS regions: DMA dest (wave base + lane*16) == readback
//     (tid*4 floats) -> NO barriers in the main loop; per-wave vmcnt only.
//   - counted waits: vmcnt(6) = keep next tile's 6 loads in flight.

#define BB 64
#define KK 5
#define NPIX 102400              // 320*320
#define QQ 4                     // quarters per image
#define SEG (NPIX / QQ)          // 25600 floats
#define THREADS 256
#define TILE 1024                // floats per tile = 256 thr * 4
#define TILES (SEG / TILE)       // 25
#define NSTR 6                   // 5 slot streams + 1 target stream
#define REC 32                   // floats per (b,q) record; 26 used
#define NVAL 26                  // 5 stats x 5 k + Tf
#define NBLK (BB * QQ)           // 256 blocks

typedef float f4 __attribute__((ext_vector_type(4)));

__global__ void hung_pass1(const float* __restrict__ slot,   // (B,K,N)
                           const float* __restrict__ tgt,    // (B,1,N)
                           float* __restrict__ ws)           // (NBLK, REC)
{
    __shared__ __align__(16) float lds[3][NSTR][TILE];

    const int bid = blockIdx.x;          // b*QQ + q
    const int b   = bid >> 2;
    const int q   = bid & 3;
    const int tid = threadIdx.x;
    const int wv  = tid >> 6;            // wave id — uniform within a wave

    const float* gs[NSTR];
    #pragma unroll
    for (int k = 0; k < KK; ++k)
        gs[k] = slot + (size_t)(b * KK + k) * NPIX + (size_t)q * SEG;
    gs[KK] = tgt + (size_t)b * NPIX + (size_t)q * SEG;

    float aX[KK]  = {0,0,0,0,0};
    float aXF[KK] = {0,0,0,0,0};
    float aS[KK]  = {0,0,0,0,0};
    float aSF[KK] = {0,0,0,0,0};
    float aPX[KK] = {0,0,0,0,0};
    float Tf = 0.f;

    // DMA one tile (6 streams x 16 B/lane) into buffer (T%3).
    // LDS dest is wave-uniform base; HW adds lane*16 -> lands at tid*4 floats.
#define ISSUE(T)                                                             \
    do {                                                                     \
        const int _t  = (T);                                                 \
        const int _bf = _t % 3;                                              \
        _Pragma("unroll")                                                    \
        for (int s = 0; s < NSTR; ++s) {                                     \
            const float* _gp = gs[s] + _t * TILE + tid * 4;                  \
            __builtin_amdgcn_global_load_lds(                                \
                (const __attribute__((address_space(1))) void*)_gp,          \
                (__attribute__((address_space(3))) void*)&lds[_bf][s][wv*256],\
                16, 0, 0);                                                   \
        }                                                                    \
    } while (0)

    ISSUE(0);
    ISSUE(1);

    for (int t = 0; t < TILES; ++t) {
        // tile t's 6 loads retired when <=6 (tile t+1's) remain outstanding
        if (t < TILES - 1) asm volatile("s_waitcnt vmcnt(6)" ::: "memory");
        else               asm volatile("s_waitcnt vmcnt(0)" ::: "memory");
        __builtin_amdgcn_sched_barrier(0);
        if (t + 2 < TILES) ISSUE(t + 2);   // refill the pipeline

        const int bf = t % 3;
        const int o  = tid * 4;            // 16B-aligned float offset
        const f4 fg4 = *reinterpret_cast<const f4*>(&lds[bf][KK][o]);
        Tf += (fg4.x + fg4.y) + (fg4.z + fg4.w);

        #pragma unroll
        for (int k = 0; k < KK; ++k) {
            const f4 x4 = *reinterpret_cast<const f4*>(&lds[bf][k][o]);
            #pragma unroll
            for (int j = 0; j < 4; ++j) {
                const float x  = x4[j];
                const float fg = fg4[j];
                const float e  = __expf(-fabsf(x));     // exp(-|x|)
                const float L  = __logf(1.0f + e);      // log1p(exp(-|x|))
                const float d  = L + fmaxf(-x, 0.0f);   // softplus(x) - x
                const float s  = __expf(-d);            // sigmoid(x)
                aPX[k] += d;
                aX[k]  += x;
                aXF[k]  = fmaf(x, fg, aXF[k]);
                aS[k]  += s;
                aSF[k]  = fmaf(s, fg, aSF[k]);
            }
        }
    }
#undef ISSUE

    // pack 26 block-partial values, reduce per-wave butterfly + LDS combine
    float v[NVAL];
    #pragma unroll
    for (int k = 0; k < KK; ++k) {
        v[k*5+0] = aX[k];  v[k*5+1] = aXF[k]; v[k*5+2] = aS[k];
        v[k*5+3] = aSF[k]; v[k*5+4] = aPX[k];
    }
    v[25] = Tf;

    #pragma unroll
    for (int jv = 0; jv < NVAL; ++jv) {
        float x = v[jv];
        #pragma unroll
        for (int off = 32; off > 0; off >>= 1) x += __shfl_down(x, off, 64);
        v[jv] = x;
    }
    __shared__ float red[THREADS / 64][NVAL];
    const int lane = threadIdx.x & 63;
    if (lane == 0) {
        #pragma unroll
        for (int jv = 0; jv < NVAL; ++jv) red[wv][jv] = v[jv];
    }
    __syncthreads();
    if (threadIdx.x < NVAL) {
        const int jv = threadIdx.x;
        ws[(size_t)bid * REC + jv] =
            red[0][jv] + red[1][jv] + red[2][jv] + red[3][jv];
    }
}

__global__ __launch_bounds__(320) void hung_pass2(const float* __restrict__ ws,
                                                  float* __restrict__ out)
{
    __shared__ float red[BB][KK][6];     // X, XF, S, SF, PX, (Tf at k==0)
    const int t = threadIdx.x;           // t == b*KK + k  (320 threads exactly)
    {
        const int b = t / KK, k = t - (t / KK) * KK;
        float v[5] = {0, 0, 0, 0, 0};
        float tf = 0.f;
        for (int q = 0; q < QQ; ++q) {
            const float* p = ws + (size_t)(b * QQ + q) * REC;
            #pragma unroll
            for (int c = 0; c < 5; ++c) v[c] += p[k * 5 + c];
            if (k == 0) tf += p[25];
        }
        #pragma unroll
        for (int c = 0; c < 5; ++c) red[b][k][c] = v[c];
        if (k == 0) red[b][0][5] = tf;
    }
    __syncthreads();
    if (t < BB) {                        // wave 0: one image per lane
        const int b = t;
        const float Tf = red[b][0][5];
        const float Tb = (float)NPIX - Tf;
        float best = 3.402823466e+38f; int kb = 0;
        float xfsum = 0.f, px = 0.f;
        #pragma unroll
        for (int k = 0; k < KK; ++k) {
            const float Sv = red[b][k][2], Iv = red[b][k][3];  // S_k, inter_fg
            const float cf = 1.f - Iv / (Sv + Tf - Iv + 1e-6f);
            const float Ib = Sv - Iv;
            const float cb = 1.f - Ib / (Sv + Tb - Ib + 1e-6f);
            const float dd = cf - cb;
            if (dd < best) { best = dd; kb = k; }  // strict < : ties -> smallest k
            xfsum += red[b][k][1];
            px    += red[b][k][4];
        }
        float res = px + xfsum - (2.f * red[b][kb][1] - red[b][kb][0]);  // - C_{k*}
        #pragma unroll
        for (int off = 32; off > 0; off >>= 1) res += __shfl_down(res, off, 64);
        if (b == 0) out[0] = res * (1.0f / 32768000.0f);   // / (B*K*N)
    }
}

extern "C" void kernel_launch(void* const* d_in, const int* in_sizes, int n_in,
                              void* d_out, int out_size, void* d_ws, size_t ws_size,
                              hipStream_t stream) {
    // setup_inputs order: fg_logits (unused by reference!), slot_logits, target
    const float* slot = (const float*)d_in[1];
    const float* tgt  = (const float*)d_in[2];
    float* out = (float*)d_out;
    float* ws  = (float*)d_ws;

    hung_pass1<<<NBLK, THREADS, 0, stream>>>(slot, tgt, ws);
    hung_pass2<<<1, 320, 0, stream>>>(ws, out);
}